// Round 13
// baseline (106.103 us; speedup 1.0000x reference)
//
#include <hip/hip_runtime.h>
#include <math.h>

#define NB 4
#define NN 512
#define DIN 128
#define DOUT 64
#define TI 2
#define CHROWS 32
#define NCH (NN / CHROWS)   // 16

typedef __attribute__((ext_vector_type(8))) short short8;
typedef __attribute__((ext_vector_type(4))) float f32x4;
typedef __attribute__((ext_vector_type(16))) float f32x16;

__device__ __forceinline__ unsigned short f2bf(float f) {
    union { float f; unsigned u; } v; v.f = f;
    unsigned r = v.u + 0x7fffu + ((v.u >> 16) & 1u);  // round-nearest-even
    return (unsigned short)(r >> 16);
}

__device__ __forceinline__ float bf2f(unsigned short u) {
    union { unsigned u; float f; } v; v.u = ((unsigned)u) << 16; return v.f;
}

// Convert x (B*N*DIN f32) to bf16 in workspace.
__global__ void x_to_bf16(const float* __restrict__ x, unsigned short* __restrict__ xbf) {
    const int idx = blockIdx.x * 256 + threadIdx.x;   // 0..65535
    float4 v = ((const float4*)x)[idx];
    ushort4 o;
    o.x = f2bf(v.x); o.y = f2bf(v.y); o.z = f2bf(v.z); o.w = f2bf(v.w);
    ((ushort4*)xbf)[idx] = o;
}

__global__ __launch_bounds__(256, 3) void gat_main(
    const float* __restrict__ x,            // [B][N][128] f32
    const unsigned short* __restrict__ xbf, // [B][N][128] bf16
    const float* __restrict__ apw,   // [64][128]
    const float* __restrict__ apb,   // [64]
    const float* __restrict__ attw,  // [64]
    const float* __restrict__ pww,   // [64][128]
    const float* __restrict__ pwb,   // [64]
    const float* __restrict__ pow_,  // [64][128]
    const float* __restrict__ pob,   // [64]
    float* __restrict__ out)         // [B*N][64] pre-BN h
{
    __shared__ float scp[2][TI][NN];     // 8 KB [oh][i][j] partial scores
    __shared__ float xis[TI][DIN];       // 1 KB query rows f32
    __shared__ float red_s[4][TI];
    __shared__ float bcs[TI];
    __shared__ float pagg[8][TI][DIN];   // 8 KB
    __shared__ float aggs[TI][DIN];      // 1 KB
    __shared__ float pr[4][DOUT];        // 1 KB

    const int t = threadIdx.x;
    const int blk = blockIdx.x;              // 0..1023
    const int b = blk >> 8;
    const int rowbase = (blk & 255) * TI;
    const float* xb = x + (size_t)b * NN * DIN;
    const unsigned short* xbb = xbf + (size_t)b * NN * DIN;

    {
        const int i = t >> 7, d = t & 127;
        xis[i][d] = xb[(size_t)(rowbase + i) * DIN + d];
    }

    const int lane = t & 63, wid = t >> 6;   // 4 waves
    const int qi = wid & 1;                  // query-row index this wave serves
    const int oh = wid >> 1;                 // o-half: o in [oh*32, oh*32+32)
    const int l31 = lane & 31;
    const int hi = lane >> 5;

    // B fragments come straight from global: row = j0 + l31, k = ks*16 + hi*8 + [0..8)
    const short8* bbase = (const short8*)(xbb + (size_t)l31 * DIN + hi * 8);
    // per-tile advance: CHROWS rows = 32*128 elems = 512 short8's

#define LOADB(BFR, CH) do {                                                     \
    const short8* bp_ = bbase + (size_t)(CH) * (CHROWS * DIN / 8);              \
    _Pragma("unroll")                                                           \
    for (int ks_ = 0; ks_ < 8; ++ks_) BFR[ks_] = bp_[ks_ * 2];                  \
} while (0)

    short8 bfr[8];
    LOADB(bfr, 0);       // issue tile-0 loads; A-prep + barrier hide latency

    __syncthreads();     // xis visible

    // A fragments afr[ks]: row o = oh*32 + l31, k = ks*16 + hi*8 + [0..8)
    short8 afr[8];
    {
        const float* wrow = apw + (size_t)(oh * 32 + l31) * DIN;
        const float* xk0 = &xis[qi][0];
        #pragma unroll
        for (int ks = 0; ks < 8; ++ks) {
            const int k0 = ks * 16 + hi * 8;
            float4 w0 = *(const float4*)(wrow + k0);
            float4 w1 = *(const float4*)(wrow + k0 + 4);
            const float* xk = xk0 + k0;
            short8 fr;
            fr[0] = (short)f2bf(w0.x * xk[0]);
            fr[1] = (short)f2bf(w0.y * xk[1]);
            fr[2] = (short)f2bf(w0.z * xk[2]);
            fr[3] = (short)f2bf(w0.w * xk[3]);
            fr[4] = (short)f2bf(w1.x * xk[4]);
            fr[5] = (short)f2bf(w1.y * xk[5]);
            fr[6] = (short)f2bf(w1.z * xk[6]);
            fr[7] = (short)f2bf(w1.w * xk[7]);
            afr[ks] = fr;
        }
    }

    // per-lane tanh constants for the 16 o's this lane's acc rows cover:
    // crow(r) = (r&3) + 8*(r>>2) + 4*hi  (verified C/D layout m74/m101)
    // w*tanh(T) = w - 2w*rcp(exp2(T*C2)+1), C2 = 2*log2(e)
    const float C2 = 2.885390081777927f;
    float awm2[16], abc[16], sumw = 0.0f;
    #pragma unroll
    for (int r = 0; r < 16; ++r) {
        const int crow = (r & 3) + 8 * (r >> 2) + 4 * hi;
        const int o = oh * 32 + crow;
        float wv = attw[o], bv = apb[o];
        awm2[r] = -2.0f * wv;
        abc[r] = bv * C2;
        sumw += wv;
    }

    f32x16 accA, accB;

#define COMPUTE(ACC, BFR) do {                                                  \
    f32x16 zz_ = {0.f,0.f,0.f,0.f,0.f,0.f,0.f,0.f,                              \
                  0.f,0.f,0.f,0.f,0.f,0.f,0.f,0.f};                             \
    ACC = zz_;                                                                  \
    _Pragma("unroll")                                                           \
    for (int ks_ = 0; ks_ < 8; ++ks_)                                           \
        ACC = __builtin_amdgcn_mfma_f32_32x32x16_bf16(afr[ks_], BFR[ks_], ACC, 0, 0, 0); \
} while (0)

#define POST(ACC, CH) do {                                                      \
    float sp_ = sumw;                                                           \
    _Pragma("unroll")                                                           \
    for (int r_ = 0; r_ < 16; ++r_) {                                           \
        float arg_ = fmaf(ACC[r_], C2, abc[r_]);                                \
        float u_, rc_;                                                          \
        asm("v_exp_f32 %0, %1" : "=v"(u_) : "v"(arg_));                         \
        float den_ = u_ + 1.0f;                                                 \
        asm("v_rcp_f32 %0, %1" : "=v"(rc_) : "v"(den_));                        \
        sp_ = fmaf(awm2[r_], rc_, sp_);                                         \
    }                                                                           \
    sp_ += __shfl_xor(sp_, 32);                                                 \
    if (lane < 32) scp[oh][qi][(CH) * 32 + l31] = sp_;                          \
} while (0)

    // tile 0
    COMPUTE(accA, bfr);
    LOADB(bfr, 1);
    // tiles 1..14, two per iteration, static acc parity, barrier-free
    for (int cb = 1; cb <= NCH - 3; cb += 2) {
        COMPUTE(accB, bfr);          // tile cb (odd)
        LOADB(bfr, cb + 1);
        POST(accA, cb - 1);
        COMPUTE(accA, bfr);          // tile cb+1 (even)
        LOADB(bfr, cb + 2);
        POST(accB, cb);
    }
    // tile 15
    COMPUTE(accB, bfr);
    POST(accA, NCH - 2);
    POST(accB, NCH - 1);
    __syncthreads();

    // softmax over j (no max-subtraction: |score| <= sum|w| ~ 8, f32-safe)
    {
        float s00 = scp[0][0][t] + scp[1][0][t];
        float s01 = scp[0][0][t + 256] + scp[1][0][t + 256];
        float s10 = scp[0][1][t] + scp[1][1][t];
        float s11 = scp[0][1][t + 256] + scp[1][1][t + 256];
        float e00 = __expf(s00), e01 = __expf(s01);
        float e10 = __expf(s10), e11 = __expf(s11);
        scp[0][0][t] = e00; scp[0][0][t + 256] = e01;   // esc[0][j]
        scp[0][1][t] = e10; scp[0][1][t + 256] = e11;   // esc[1][j]
        float ss0 = e00 + e01, ss1 = e10 + e11;
        #pragma unroll
        for (int m = 1; m < 64; m <<= 1) {
            ss0 += __shfl_xor(ss0, m);
            ss1 += __shfl_xor(ss1, m);
        }
        if (lane == 0) { red_s[wid][0] = ss0; red_s[wid][1] = ss1; }
    }
    __syncthreads();
    if (t < TI) {
        float sm = red_s[0][t] + red_s[1][t] + red_s[2][t] + red_s[3][t];
        bcs[t] = 1.0f / sm;
    }
    __syncthreads();

    // agg[i][d] = invs_i * sum_j e[i][j] * x[b,j,d]  — ushort4-vectorized
    const float* esc0 = &scp[0][0][0];
    const float* esc1 = &scp[0][1][0];
    {
        const int d0 = (t & 31) * 4, q = t >> 5;   // 8 groups of 64 j
        const unsigned short* xc = xbb + d0;
        float a0[4] = {0.f, 0.f, 0.f, 0.f};
        float a1[4] = {0.f, 0.f, 0.f, 0.f};
        #pragma unroll 4
        for (int jj = q * 64; jj < q * 64 + 64; ++jj) {
            ushort4 xv = *(const ushort4*)(xc + (size_t)jj * DIN);
            float e0v = esc0[jj], e1v = esc1[jj];
            float x0 = bf2f(xv.x), x1 = bf2f(xv.y);
            float x2 = bf2f(xv.z), x3 = bf2f(xv.w);
            a0[0] = fmaf(e0v, x0, a0[0]); a0[1] = fmaf(e0v, x1, a0[1]);
            a0[2] = fmaf(e0v, x2, a0[2]); a0[3] = fmaf(e0v, x3, a0[3]);
            a1[0] = fmaf(e1v, x0, a1[0]); a1[1] = fmaf(e1v, x1, a1[1]);
            a1[2] = fmaf(e1v, x2, a1[2]); a1[3] = fmaf(e1v, x3, a1[3]);
        }
        #pragma unroll
        for (int c = 0; c < 4; ++c) {
            pagg[q][0][d0 + c] = a0[c];
            pagg[q][1][d0 + c] = a1[c];
        }
    }
    __syncthreads();
    {
        const int i = t >> 7, d = t & 127;
        float s = 0.f;
        #pragma unroll
        for (int q = 0; q < 8; ++q) s += pagg[q][i][d];
        aggs[i][d] = s * bcs[i];
    }
    __syncthreads();

    // projections: pi = t>>6 in 0..3 -> i = pi>>1, d-half = pi&1 (64 d each)
    {
        const int o = t & 63, pi = t >> 6;
        const int i = pi >> 1, part = pi & 1;
        const float* w1 = pww + (size_t)o * DIN + part * 64;
        const float* w2 = pow_ + (size_t)o * DIN + part * 64;
        const float* ag = &aggs[i][part * 64];
        const float* xr = &xis[i][part * 64];
        float sum = 0.0f;
        #pragma unroll
        for (int dd = 0; dd < 64; ++dd)
            sum += w1[dd] * ag[dd] + w2[dd] * xr[dd];
        pr[pi][o] = sum;
    }
    __syncthreads();
    if (t < TI * DOUT) {
        const int i = t >> 6, o = t & 63;
        float h = pr[i * 2][o] + pr[i * 2 + 1][o] + pwb[o] + pob[o];
        out[(size_t)(b * NN + rowbase + i) * DOUT + o] = h;
    }
#undef COMPUTE
#undef POST
#undef LOADB
}

// Per-channel batch stats over (B*N, 64); deterministic tree reduction.
__global__ void bn_stats(const float* __restrict__ h, float* __restrict__ stats) {
    const int c = blockIdx.x;
    const int t = threadIdx.x;
    float s = 0.f, s2 = 0.f;
    for (int r = t; r < NB * NN; r += 256) {
        float v = h[(size_t)r * DOUT + c];
        s += v; s2 += v * v;
    }
    __shared__ float rs[256], rs2[256];
    rs[t] = s; rs2[t] = s2;
    __syncthreads();
    for (int k = 128; k > 0; k >>= 1) {
        if (t < k) { rs[t] += rs[t + k]; rs2[t] += rs2[t + k]; }
        __syncthreads();
    }
    if (t == 0) {
        const float inv_n = 1.0f / (float)(NB * NN);
        float mean = rs[0] * inv_n;
        float var = rs2[0] * inv_n - mean * mean;   // biased, as torch BN
        stats[c] = mean;
        stats[DOUT + c] = rsqrtf(var + 1e-5f);
    }
}

__global__ void bn_selu(float* __restrict__ out, const float* __restrict__ stats,
                        const float* __restrict__ gamma, const float* __restrict__ beta) {
    const int idx = blockIdx.x * 256 + threadIdx.x;
    const int c = idx & 63;
    float v = out[idx];
    float y = (v - stats[c]) * stats[DOUT + c] * gamma[c] + beta[c];
    const float scale = 1.0507009873554805f;
    const float alpha = 1.6732632423543772f;
    out[idx] = y > 0.0f ? scale * y : scale * alpha * (__expf(y) - 1.0f);
}

extern "C" void kernel_launch(void* const* d_in, const int* in_sizes, int n_in,
                              void* d_out, int out_size, void* d_ws, size_t ws_size,
                              hipStream_t stream) {
    const float* x    = (const float*)d_in[0];
    const float* apw  = (const float*)d_in[1];
    const float* apb  = (const float*)d_in[2];
    const float* attw = (const float*)d_in[3];
    const float* pww  = (const float*)d_in[4];
    const float* pwb  = (const float*)d_in[5];
    const float* pow_ = (const float*)d_in[6];
    const float* pob  = (const float*)d_in[7];
    const float* gmm  = (const float*)d_in[8];
    const float* bta  = (const float*)d_in[9];
    float* out = (float*)d_out;
    float* stats = (float*)d_ws;                                 // 128 floats
    unsigned short* xbf = (unsigned short*)((char*)d_ws + 1024); // 512 KB bf16 x

    x_to_bf16<<<256, 256, 0, stream>>>(x, xbf);
    gat_main<<<NB * NN / TI, 256, 0, stream>>>(x, xbf, apw, apb, attw, pww, pwb, pow_, pob, out);
    bn_stats<<<DOUT, 256, 0, stream>>>(out, stats);
    bn_selu<<<(NB * NN * DOUT) / 256, 256, 0, stream>>>(out, stats, gmm, bta);
}

// Round 14
// 77.078 us; speedup vs baseline: 1.3766x; 1.3766x over previous
//
#include <hip/hip_runtime.h>
#include <math.h>

#define NB 4
#define NN 512
#define DIN 128
#define DOUT 64
#define TI 2
#define CHROWS 32
#define NCHL 8          // chunks per block (j-half)
#define NTOT (NB * NN)  // 2048 rows

typedef __attribute__((ext_vector_type(8))) short short8;
typedef __attribute__((ext_vector_type(8))) unsigned short ushort8;
typedef __attribute__((ext_vector_type(16))) float f32x16;

__device__ __forceinline__ unsigned short f2bf(float f) {
    union { float f; unsigned u; } v; v.f = f;
    unsigned r = v.u + 0x7fffu + ((v.u >> 16) & 1u);  // round-nearest-even
    return (unsigned short)(r >> 16);
}

__device__ __forceinline__ float bf2f(unsigned short u) {
    union { unsigned u; float f; } v; v.u = ((unsigned)u) << 16; return v.f;
}

// Convert x (B*N*DIN f32) to bf16 in workspace.
__global__ void x_to_bf16(const float* __restrict__ x, unsigned short* __restrict__ xbf) {
    const int idx = blockIdx.x * 256 + threadIdx.x;   // 0..65535
    float4 v = ((const float4*)x)[idx];
    ushort4 o;
    o.x = f2bf(v.x); o.y = f2bf(v.y); o.z = f2bf(v.z); o.w = f2bf(v.w);
    ((ushort4*)xbf)[idx] = o;
}

// Scores + exp + PARTIAL softmax (num/den) for one (row-pair, j-half).
__global__ __launch_bounds__(256, 3) void gat_main(
    const float* __restrict__ x,            // [B][N][128] f32
    const unsigned short* __restrict__ xbf, // [B][N][128] bf16
    const float* __restrict__ apw,   // [64][128]
    const float* __restrict__ apb,   // [64]
    const float* __restrict__ attw,  // [64]
    float* __restrict__ pnum,        // [2][NTOT][128]
    float* __restrict__ pden)        // [2][NTOT]
{
    __shared__ unsigned short xt[2][CHROWS * DIN];  // 16 KB dbuf tiles
    __shared__ float scp[2][TI][256];               // 4 KB [oh][i][jloc]
    __shared__ float xis[TI][DIN];                  // 1 KB query rows f32
    __shared__ float red_s[4][TI];

    float* pagg = (float*)&xt[0][0];                // [8][TI][128] 8 KB alias

    const int t = threadIdx.x;
    const int blk = blockIdx.x;              // 0..2047
    const int jh = blk & 1;                  // j-half
    const int rp = blk >> 1;                 // row-pair 0..1023
    const int b = rp >> 8;
    const int rowbase = (rp & 255) * TI;
    const int rid0 = rp * TI;                // global row id base
    const float* xb = x + (size_t)b * NN * DIN;
    const unsigned short* xbb = xbf + (size_t)b * NN * DIN;

    {
        const int i = t >> 7, d = t & 127;
        xis[i][d] = xb[(size_t)(rowbase + i) * DIN + d];
    }

    const int lane = t & 63, wid = t >> 6;   // 4 waves
    const int qi = wid & 1;                  // query-row index this wave serves
    const int oh = wid >> 1;                 // o-half: o in [oh*32, oh*32+32)
    const int l31 = lane & 31;
    const int hi = lane >> 5;

    // staging: 2 ushort8 (32 B) per thread per chunk, granule-XOR swizzle
    const int r0 = t >> 4, g0 = t & 15;
    const int st_off0 = r0 * 256 + ((g0 ^ (r0 & 7)) << 4);
    const int r1 = 16 + r0;
    const int st_off1 = r1 * 256 + ((g0 ^ (r1 & 7)) << 4);

    // read offsets: row = l31, logical granule = ks*2 + hi
    int rdoff[8];
    #pragma unroll
    for (int ks = 0; ks < 8; ++ks)
        rdoff[ks] = l31 * 256 + (((ks * 2 + hi) ^ (l31 & 7)) << 4);

    // issue chunk-0 loads early; xis barrier + A-prep hide the latency
    ushort8 v0a = ((const ushort8*)xbb)[(jh * NCHL) * 512 + t];
    ushort8 v0b = ((const ushort8*)xbb)[(jh * NCHL) * 512 + t + 256];
    __syncthreads();   // xis visible

    // A fragments afr[ks]: row o = oh*32 + l31, k = ks*16 + hi*8 + [0..8)
    short8 afr[8];
    {
        const float* wrow = apw + (size_t)(oh * 32 + l31) * DIN;
        const float* xk0 = &xis[qi][0];
        #pragma unroll
        for (int ks = 0; ks < 8; ++ks) {
            const int k0 = ks * 16 + hi * 8;
            float4 w0 = *(const float4*)(wrow + k0);
            float4 w1 = *(const float4*)(wrow + k0 + 4);
            const float* xk = xk0 + k0;
            short8 fr;
            fr[0] = (short)f2bf(w0.x * xk[0]);
            fr[1] = (short)f2bf(w0.y * xk[1]);
            fr[2] = (short)f2bf(w0.z * xk[2]);
            fr[3] = (short)f2bf(w0.w * xk[3]);
            fr[4] = (short)f2bf(w1.x * xk[4]);
            fr[5] = (short)f2bf(w1.y * xk[5]);
            fr[6] = (short)f2bf(w1.z * xk[6]);
            fr[7] = (short)f2bf(w1.w * xk[7]);
            afr[ks] = fr;
        }
    }

    // per-lane tanh constants; crow(r) = (r&3)+8*(r>>2)+4*hi (m74/m101 layout)
    // w*tanh(T) = w - 2w*rcp(exp2(T*C2)+1), C2 = 2*log2(e)
    const float C2 = 2.885390081777927f;
    float awm2[16], abc[16], sumw = 0.0f;
    #pragma unroll
    for (int r = 0; r < 16; ++r) {
        const int crow = (r & 3) + 8 * (r >> 2) + 4 * hi;
        const int o = oh * 32 + crow;
        float wv = attw[o], bv = apb[o];
        awm2[r] = -2.0f * wv;
        abc[r] = bv * C2;
        sumw += wv;
    }

    *(ushort8*)((char*)&xt[0][0] + st_off0) = v0a;
    *(ushort8*)((char*)&xt[0][0] + st_off1) = v0b;
    __syncthreads();   // xt[0] visible

    f32x16 accA, accB;

#define COMPUTE(ACC, BUF) do {                                                  \
    f32x16 zz_ = {0.f,0.f,0.f,0.f,0.f,0.f,0.f,0.f,                              \
                  0.f,0.f,0.f,0.f,0.f,0.f,0.f,0.f};                             \
    ACC = zz_;                                                                  \
    _Pragma("unroll")                                                           \
    for (int ks_ = 0; ks_ < 8; ++ks_) {                                         \
        short8 bk_ = *(const short8*)((const char*)&xt[BUF][0] + rdoff[ks_]);   \
        ACC = __builtin_amdgcn_mfma_f32_32x32x16_bf16(afr[ks_], bk_, ACC, 0, 0, 0); \
    }                                                                           \
} while (0)

#define POST(ACC, CH) do {                                                      \
    float sp_ = sumw;                                                           \
    _Pragma("unroll")                                                           \
    for (int r_ = 0; r_ < 16; ++r_) {                                           \
        float arg_ = fmaf(ACC[r_], C2, abc[r_]);                                \
        float u_, rc_;                                                          \
        asm("v_exp_f32 %0, %1" : "=v"(u_) : "v"(arg_));                         \
        float den_ = u_ + 1.0f;                                                 \
        asm("v_rcp_f32 %0, %1" : "=v"(rc_) : "v"(den_));                        \
        sp_ = fmaf(awm2[r_], rc_, sp_);                                         \
    }                                                                           \
    sp_ += __shfl_xor(sp_, 32);                                                 \
    if (lane < 32) scp[oh][qi][(CH) * 32 + l31] = sp_;                          \
} while (0)

#define STAGE(BUF, CH) do {                                                     \
    ushort8 va_ = ((const ushort8*)xbb)[(jh * NCHL + (CH)) * 512 + t];          \
    ushort8 vb_ = ((const ushort8*)xbb)[(jh * NCHL + (CH)) * 512 + t + 256];    \
    *(ushort8*)((char*)&xt[BUF][0] + st_off0) = va_;                            \
    *(ushort8*)((char*)&xt[BUF][0] + st_off1) = vb_;                            \
} while (0)

    // chunk 0
    {
        COMPUTE(accA, 0);
        STAGE(1, 1);
        __syncthreads();
    }
    // chunks 1..6, two per iteration, static buffer parity
    for (int cb = 1; cb <= NCHL - 3; cb += 2) {
        {
            COMPUTE(accB, 1);           // chunk cb (odd)
            POST(accA, cb - 1);
            STAGE(0, cb + 1);
            __syncthreads();
        }
        {
            COMPUTE(accA, 0);           // chunk cb+1 (even)
            POST(accB, cb);
            STAGE(1, cb + 2);
            __syncthreads();
        }
    }
    // chunk 7
    COMPUTE(accB, 1);
    POST(accA, NCHL - 2);
    POST(accB, NCHL - 1);
    __syncthreads();

    // exp + partial denominator (no max-subtraction: |score| <= sum|w| ~ 8)
    {
        float s0 = scp[0][0][t] + scp[1][0][t];
        float s1 = scp[0][1][t] + scp[1][1][t];
        float e0 = __expf(s0), e1 = __expf(s1);
        scp[0][0][t] = e0;   // esc[0][jloc]
        scp[0][1][t] = e1;   // esc[1][jloc]
        float ss0 = e0, ss1 = e1;
        #pragma unroll
        for (int m = 1; m < 64; m <<= 1) {
            ss0 += __shfl_xor(ss0, m);
            ss1 += __shfl_xor(ss1, m);
        }
        if (lane == 0) { red_s[wid][0] = ss0; red_s[wid][1] = ss1; }
    }
    __syncthreads();
    if (t < TI) {
        float den = red_s[0][t] + red_s[1][t] + red_s[2][t] + red_s[3][t];
        pden[jh * NTOT + rid0 + t] = den;
    }

    // partial numerator over this block's 256 j  — ushort4-vectorized
    const float* esc0 = &scp[0][0][0];
    const float* esc1 = &scp[0][1][0];
    {
        const int d0 = (t & 31) * 4, q = t >> 5;   // 8 groups of 32 j
        const unsigned short* xc = xbb + (size_t)(jh * 256) * DIN + d0;
        float a0[4] = {0.f, 0.f, 0.f, 0.f};
        float a1[4] = {0.f, 0.f, 0.f, 0.f};
        #pragma unroll 4
        for (int jj = q * 32; jj < q * 32 + 32; ++jj) {
            ushort4 xv = *(const ushort4*)(xc + (size_t)jj * DIN);
            float e0v = esc0[jj], e1v = esc1[jj];
            float x0 = bf2f(xv.x), x1 = bf2f(xv.y);
            float x2 = bf2f(xv.z), x3 = bf2f(xv.w);
            a0[0] = fmaf(e0v, x0, a0[0]); a0[1] = fmaf(e0v, x1, a0[1]);
            a0[2] = fmaf(e0v, x2, a0[2]); a0[3] = fmaf(e0v, x3, a0[3]);
            a1[0] = fmaf(e1v, x0, a1[0]); a1[1] = fmaf(e1v, x1, a1[1]);
            a1[2] = fmaf(e1v, x2, a1[2]); a1[3] = fmaf(e1v, x3, a1[3]);
        }
        #pragma unroll
        for (int c = 0; c < 4; ++c) {
            pagg[(q * TI + 0) * DIN + d0 + c] = a0[c];
            pagg[(q * TI + 1) * DIN + d0 + c] = a1[c];
        }
    }
    __syncthreads();
    {
        const int i = t >> 7, d = t & 127;
        float s = 0.f;
        #pragma unroll
        for (int q = 0; q < 8; ++q) s += pagg[(q * TI + i) * DIN + d];
        pnum[(size_t)(jh * NTOT + rid0 + i) * DIN + d] = s;
    }
#undef COMPUTE
#undef POST
#undef STAGE
}

// Combine the two j-half partials, normalize, apply both projections.
__global__ __launch_bounds__(256) void combine_proj(
    const float* __restrict__ x,
    const float* __restrict__ pnum, const float* __restrict__ pden,
    const float* __restrict__ pww, const float* __restrict__ pwb,
    const float* __restrict__ pow_, const float* __restrict__ pob,
    float* __restrict__ out)
{
    __shared__ float aggL[4][DIN];
    __shared__ float xiL[4][DIN];
    const int t = threadIdx.x, lane = t & 63, w = t >> 6;
    const int rid = blockIdx.x * 4 + w;        // 0..2047
    {
        const int d = lane;
        float inv = 1.0f / (pden[rid] + pden[NTOT + rid]);
        float n0 = pnum[(size_t)rid * DIN + d] + pnum[(size_t)(NTOT + rid) * DIN + d];
        float n1 = pnum[(size_t)rid * DIN + d + 64] + pnum[(size_t)(NTOT + rid) * DIN + d + 64];
        aggL[w][d] = n0 * inv;
        aggL[w][d + 64] = n1 * inv;
        xiL[w][d] = x[(size_t)rid * DIN + d];
        xiL[w][d + 64] = x[(size_t)rid * DIN + d + 64];
    }
    // same-wave LDS RAW: compiler inserts lgkmcnt wait; no barrier needed
    const int o = lane;
    const float* w1 = pww + (size_t)o * DIN;
    const float* w2 = pow_ + (size_t)o * DIN;
    float sum = 0.0f;
    #pragma unroll 8
    for (int dd = 0; dd < DIN; ++dd)
        sum += w1[dd] * aggL[w][dd] + w2[dd] * xiL[w][dd];
    out[(size_t)rid * DOUT + o] = sum + pwb[o] + pob[o];
}

// Per-channel batch stats over (B*N, 64); deterministic tree reduction.
__global__ void bn_stats(const float* __restrict__ h, float* __restrict__ stats) {
    const int c = blockIdx.x;
    const int t = threadIdx.x;
    float s = 0.f, s2 = 0.f;
    for (int r = t; r < NTOT; r += 256) {
        float v = h[(size_t)r * DOUT + c];
        s += v; s2 += v * v;
    }
    __shared__ float rs[256], rs2[256];
    rs[t] = s; rs2[t] = s2;
    __syncthreads();
    for (int k = 128; k > 0; k >>= 1) {
        if (t < k) { rs[t] += rs[t + k]; rs2[t] += rs2[t + k]; }
        __syncthreads();
    }
    if (t == 0) {
        const float inv_n = 1.0f / (float)NTOT;
        float mean = rs[0] * inv_n;
        float var = rs2[0] * inv_n - mean * mean;   // biased, as torch BN
        stats[c] = mean;
        stats[DOUT + c] = rsqrtf(var + 1e-5f);
    }
}

__global__ void bn_selu(float* __restrict__ out, const float* __restrict__ stats,
                        const float* __restrict__ gamma, const float* __restrict__ beta) {
    const int idx = blockIdx.x * 256 + threadIdx.x;
    const int c = idx & 63;
    float v = out[idx];
    float y = (v - stats[c]) * stats[DOUT + c] * gamma[c] + beta[c];
    const float scale = 1.0507009873554805f;
    const float alpha = 1.6732632423543772f;
    out[idx] = y > 0.0f ? scale * y : scale * alpha * (__expf(y) - 1.0f);
}

extern "C" void kernel_launch(void* const* d_in, const int* in_sizes, int n_in,
                              void* d_out, int out_size, void* d_ws, size_t ws_size,
                              hipStream_t stream) {
    const float* x    = (const float*)d_in[0];
    const float* apw  = (const float*)d_in[1];
    const float* apb  = (const float*)d_in[2];
    const float* attw = (const float*)d_in[3];
    const float* pww  = (const float*)d_in[4];
    const float* pwb  = (const float*)d_in[5];
    const float* pow_ = (const float*)d_in[6];
    const float* pob  = (const float*)d_in[7];
    const float* gmm  = (const float*)d_in[8];
    const float* bta  = (const float*)d_in[9];
    float* out = (float*)d_out;

    char* ws = (char*)d_ws;
    float* stats = (float*)ws;                               // 512 B (pad 1 KB)
    unsigned short* xbf = (unsigned short*)(ws + 1024);      // 512 KB
    float* pnum = (float*)(ws + 528384);                     // 2 MB  [2][2048][128]
    float* pden = (float*)(ws + 528384 + 2097152);           // 16 KB [2][2048]

    x_to_bf16<<<256, 256, 0, stream>>>(x, xbf);
    gat_main<<<2 * NTOT / TI, 256, 0, stream>>>(x, xbf, apw, apb, attw, pnum, pden);
    combine_proj<<<NTOT / 4, 256, 0, stream>>>(x, pnum, pden, pww, pwb, pow_, pob, out);
    bn_stats<<<DOUT, 256, 0, stream>>>(out, stats);
    bn_selu<<<(NTOT * DOUT) / 256, 256, 0, stream>>>(out, stats, gmm, bta);
}

// Round 15
// 71.261 us; speedup vs baseline: 1.4890x; 1.0816x over previous
//
#include <hip/hip_runtime.h>
#include <math.h>

#define NB 4
#define NN 512
#define DIN 128
#define DOUT 64
#define TI 2
#define CHROWS 32
#define NCHL 8          // chunks per block (j-half)
#define NTOT (NB * NN)  // 2048 rows

typedef __attribute__((ext_vector_type(8))) short short8;
typedef __attribute__((ext_vector_type(8))) unsigned short ushort8;
typedef __attribute__((ext_vector_type(16))) float f32x16;

__device__ __forceinline__ unsigned short f2bf(float f) {
    union { float f; unsigned u; } v; v.f = f;
    unsigned r = v.u + 0x7fffu + ((v.u >> 16) & 1u);  // round-nearest-even
    return (unsigned short)(r >> 16);
}

__device__ __forceinline__ float bf2f(unsigned short u) {
    union { unsigned u; float f; } v; v.u = ((unsigned)u) << 16; return v.f;
}

// Convert x (B*N*DIN f32) to bf16 in workspace.
__global__ void x_to_bf16(const float* __restrict__ x, unsigned short* __restrict__ xbf) {
    const int idx = blockIdx.x * 256 + threadIdx.x;   // 0..65535
    float4 v = ((const float4*)x)[idx];
    ushort4 o;
    o.x = f2bf(v.x); o.y = f2bf(v.y); o.z = f2bf(v.z); o.w = f2bf(v.w);
    ((ushort4*)xbf)[idx] = o;
}

// Scores + exp + PARTIAL softmax (num/den) for one (row-pair, j-half).
__global__ __launch_bounds__(256, 3) void gat_main(
    const float* __restrict__ x,            // [B][N][128] f32
    const unsigned short* __restrict__ xbf, // [B][N][128] bf16
    const float* __restrict__ apw,   // [64][128]
    const float* __restrict__ apb,   // [64]
    const float* __restrict__ attw,  // [64]
    float* __restrict__ pnum,        // [2][NTOT][128]
    float* __restrict__ pden)        // [2][NTOT]
{
    __shared__ unsigned short xt[2][CHROWS * DIN];  // 16 KB dbuf tiles
    __shared__ float scp[2][TI][256];               // 4 KB [oh][i][jloc]
    __shared__ float xis[TI][DIN];                  // 1 KB query rows f32
    __shared__ float red_s[4][TI];

    float* pagg = (float*)&xt[0][0];                // [8][TI][128] 8 KB alias

    const int t = threadIdx.x;
    const int blk = blockIdx.x;              // 0..2047
    const int jh = blk & 1;                  // j-half
    const int rp = blk >> 1;                 // row-pair 0..1023
    const int b = rp >> 8;
    const int rowbase = (rp & 255) * TI;
    const int rid0 = rp * TI;                // global row id base
    const float* xb = x + (size_t)b * NN * DIN;
    const unsigned short* xbb = xbf + (size_t)b * NN * DIN;

    {
        const int i = t >> 7, d = t & 127;
        xis[i][d] = xb[(size_t)(rowbase + i) * DIN + d];
    }

    const int lane = t & 63, wid = t >> 6;   // 4 waves
    const int qi = wid & 1;                  // query-row index this wave serves
    const int oh = wid >> 1;                 // o-half: o in [oh*32, oh*32+32)
    const int l31 = lane & 31;
    const int hi = lane >> 5;

    // staging: 2 ushort8 (32 B) per thread per chunk, granule-XOR swizzle
    const int r0 = t >> 4, g0 = t & 15;
    const int st_off0 = r0 * 256 + ((g0 ^ (r0 & 7)) << 4);
    const int r1 = 16 + r0;
    const int st_off1 = r1 * 256 + ((g0 ^ (r1 & 7)) << 4);

    // read offsets: row = l31, logical granule = ks*2 + hi
    int rdoff[8];
    #pragma unroll
    for (int ks = 0; ks < 8; ++ks)
        rdoff[ks] = l31 * 256 + (((ks * 2 + hi) ^ (l31 & 7)) << 4);

    // issue chunk-0 loads early; xis barrier + A-prep hide the latency
    ushort8 v0a = ((const ushort8*)xbb)[(jh * NCHL) * 512 + t];
    ushort8 v0b = ((const ushort8*)xbb)[(jh * NCHL) * 512 + t + 256];
    __syncthreads();   // xis visible

    // A fragments afr[ks]: row o = oh*32 + l31, k = ks*16 + hi*8 + [0..8)
    short8 afr[8];
    {
        const float* wrow = apw + (size_t)(oh * 32 + l31) * DIN;
        const float* xk0 = &xis[qi][0];
        #pragma unroll
        for (int ks = 0; ks < 8; ++ks) {
            const int k0 = ks * 16 + hi * 8;
            float4 w0 = *(const float4*)(wrow + k0);
            float4 w1 = *(const float4*)(wrow + k0 + 4);
            const float* xk = xk0 + k0;
            short8 fr;
            fr[0] = (short)f2bf(w0.x * xk[0]);
            fr[1] = (short)f2bf(w0.y * xk[1]);
            fr[2] = (short)f2bf(w0.z * xk[2]);
            fr[3] = (short)f2bf(w0.w * xk[3]);
            fr[4] = (short)f2bf(w1.x * xk[4]);
            fr[5] = (short)f2bf(w1.y * xk[5]);
            fr[6] = (short)f2bf(w1.z * xk[6]);
            fr[7] = (short)f2bf(w1.w * xk[7]);
            afr[ks] = fr;
        }
    }

    // per-lane tanh constants; crow(r) = (r&3)+8*(r>>2)+4*hi (m74/m101 layout)
    // w*tanh(T) = w - 2w*rcp(exp2(T*C2)+1), C2 = 2*log2(e)
    const float C2 = 2.885390081777927f;
    float awm2[16], abc[16], sumw = 0.0f;
    #pragma unroll
    for (int r = 0; r < 16; ++r) {
        const int crow = (r & 3) + 8 * (r >> 2) + 4 * hi;
        const int o = oh * 32 + crow;
        float wv = attw[o], bv = apb[o];
        awm2[r] = -2.0f * wv;
        abc[r] = bv * C2;
        sumw += wv;
    }

    *(ushort8*)((char*)&xt[0][0] + st_off0) = v0a;
    *(ushort8*)((char*)&xt[0][0] + st_off1) = v0b;
    __syncthreads();   // xt[0] visible

    f32x16 accA, accB;
    ushort8 nva, nvb;   // in-flight staging registers (T14 issue-early/write-late)

#define COMPUTE(ACC, BUF) do {                                                  \
    f32x16 zz_ = {0.f,0.f,0.f,0.f,0.f,0.f,0.f,0.f,                              \
                  0.f,0.f,0.f,0.f,0.f,0.f,0.f,0.f};                             \
    ACC = zz_;                                                                  \
    _Pragma("unroll")                                                           \
    for (int ks_ = 0; ks_ < 8; ++ks_) {                                         \
        short8 bk_ = *(const short8*)((const char*)&xt[BUF][0] + rdoff[ks_]);   \
        ACC = __builtin_amdgcn_mfma_f32_32x32x16_bf16(afr[ks_], bk_, ACC, 0, 0, 0); \
    }                                                                           \
} while (0)

#define POST(ACC, CH) do {                                                      \
    float sp_ = sumw;                                                           \
    _Pragma("unroll")                                                           \
    for (int r_ = 0; r_ < 16; ++r_) {                                           \
        float arg_ = fmaf(ACC[r_], C2, abc[r_]);                                \
        float u_, rc_;                                                          \
        asm("v_exp_f32 %0, %1" : "=v"(u_) : "v"(arg_));                         \
        float den_ = u_ + 1.0f;                                                 \
        asm("v_rcp_f32 %0, %1" : "=v"(rc_) : "v"(den_));                        \
        sp_ = fmaf(awm2[r_], rc_, sp_);                                         \
    }                                                                           \
    sp_ += __shfl_xor(sp_, 32);                                                 \
    if (lane < 32) scp[oh][qi][(CH) * 32 + l31] = sp_;                          \
} while (0)

#define LOADR(CH) do {                                                          \
    nva = ((const ushort8*)xbb)[(jh * NCHL + (CH)) * 512 + t];                  \
    nvb = ((const ushort8*)xbb)[(jh * NCHL + (CH)) * 512 + t + 256];            \
} while (0)

#define WRITES(BUF) do {                                                        \
    *(ushort8*)((char*)&xt[BUF][0] + st_off0) = nva;                            \
    *(ushort8*)((char*)&xt[BUF][0] + st_off1) = nvb;                            \
} while (0)

    // chunk 0: issue chunk-1 loads BEFORE compute; write AFTER
    LOADR(1);
    COMPUTE(accA, 0);
    WRITES(1);
    __syncthreads();
    // chunks 1..6, two per iteration, static buffer parity
    for (int cb = 1; cb <= NCHL - 3; cb += 2) {
        LOADR(cb + 1);
        COMPUTE(accB, 1);           // chunk cb (odd)
        POST(accA, cb - 1);
        WRITES(0);
        __syncthreads();
        LOADR(cb + 2);
        COMPUTE(accA, 0);           // chunk cb+1 (even)
        POST(accB, cb);
        WRITES(1);
        __syncthreads();
    }
    // chunk 7
    COMPUTE(accB, 1);
    POST(accA, NCHL - 2);
    POST(accB, NCHL - 1);
    __syncthreads();

    // exp + partial denominator (no max-subtraction: |score| <= sum|w| ~ 8)
    {
        float s0 = scp[0][0][t] + scp[1][0][t];
        float s1 = scp[0][1][t] + scp[1][1][t];
        float e0 = __expf(s0), e1 = __expf(s1);
        scp[0][0][t] = e0;   // esc[0][jloc]
        scp[0][1][t] = e1;   // esc[1][jloc]
        float ss0 = e0, ss1 = e1;
        #pragma unroll
        for (int m = 1; m < 64; m <<= 1) {
            ss0 += __shfl_xor(ss0, m);
            ss1 += __shfl_xor(ss1, m);
        }
        if (lane == 0) { red_s[wid][0] = ss0; red_s[wid][1] = ss1; }
    }
    __syncthreads();
    if (t < TI) {
        float den = red_s[0][t] + red_s[1][t] + red_s[2][t] + red_s[3][t];
        pden[jh * NTOT + rid0 + t] = den;
    }

    // partial numerator over this block's 256 j  — ushort4-vectorized
    const float* esc0 = &scp[0][0][0];
    const float* esc1 = &scp[0][1][0];
    {
        const int d0 = (t & 31) * 4, q = t >> 5;   // 8 groups of 32 j
        const unsigned short* xc = xbb + (size_t)(jh * 256) * DIN + d0;
        float a0[4] = {0.f, 0.f, 0.f, 0.f};
        float a1[4] = {0.f, 0.f, 0.f, 0.f};
        #pragma unroll 4
        for (int jj = q * 32; jj < q * 32 + 32; ++jj) {
            ushort4 xv = *(const ushort4*)(xc + (size_t)jj * DIN);
            float e0v = esc0[jj], e1v = esc1[jj];
            float x0 = bf2f(xv.x), x1 = bf2f(xv.y);
            float x2 = bf2f(xv.z), x3 = bf2f(xv.w);
            a0[0] = fmaf(e0v, x0, a0[0]); a0[1] = fmaf(e0v, x1, a0[1]);
            a0[2] = fmaf(e0v, x2, a0[2]); a0[3] = fmaf(e0v, x3, a0[3]);
            a1[0] = fmaf(e1v, x0, a1[0]); a1[1] = fmaf(e1v, x1, a1[1]);
            a1[2] = fmaf(e1v, x2, a1[2]); a1[3] = fmaf(e1v, x3, a1[3]);
        }
        #pragma unroll
        for (int c = 0; c < 4; ++c) {
            pagg[(q * TI + 0) * DIN + d0 + c] = a0[c];
            pagg[(q * TI + 1) * DIN + d0 + c] = a1[c];
        }
    }
    __syncthreads();
    {
        const int i = t >> 7, d = t & 127;
        float s = 0.f;
        #pragma unroll
        for (int q = 0; q < 8; ++q) s += pagg[(q * TI + i) * DIN + d];
        pnum[(size_t)(jh * NTOT + rid0 + i) * DIN + d] = s;
    }
#undef COMPUTE
#undef POST
#undef LOADR
#undef WRITES
}

// Combine j-half partials, normalize, apply both projections.
// 128 blocks x 16 rows; weights staged in LDS (coalesced), padded vs bank conflicts.
__global__ __launch_bounds__(256, 2) void combine_proj(
    const float* __restrict__ x,
    const float* __restrict__ pnum, const float* __restrict__ pden,
    const float* __restrict__ pww, const float* __restrict__ pwb,
    const float* __restrict__ pow_, const float* __restrict__ pob,
    float* __restrict__ out)
{
    __shared__ float wL[DOUT][DIN + 1];   // 33 KB (one matrix at a time)
    __shared__ float vL[16][DIN];         // 8 KB (num, then xi)
    __shared__ float invL[16];

    const int t = threadIdx.x;
    const int rbase = blockIdx.x * 16;
    const int o = t & 63, rq = t >> 6;    // per-wave uniform rq

    // stage W1 + unnormalized num + inv-denominators (all coalesced)
    for (int k = t; k < DOUT * DIN; k += 256) wL[k >> 7][k & 127] = pww[k];
    for (int k = t; k < 16 * DIN; k += 256) {
        const int i = k >> 7, d = k & 127;
        const int r = rbase + i;
        vL[i][d] = pnum[(size_t)r * DIN + d] + pnum[(size_t)(NTOT + r) * DIN + d];
    }
    if (t < 16) {
        const int r = rbase + t;
        invL[t] = 1.0f / (pden[r] + pden[NTOT + r]);
    }
    __syncthreads();

    // phase 1: accp[rr] = W1[o,:] . num[row rq+rr*4]
    float accp[4] = {0.f, 0.f, 0.f, 0.f};
    #pragma unroll 4
    for (int d = 0; d < DIN; ++d) {
        float w = wL[o][d];   // (o+d)%32 banks -> 2 lanes/bank, free
        #pragma unroll
        for (int rr = 0; rr < 4; ++rr)
            accp[rr] = fmaf(w, vL[rq + rr * 4][d], accp[rr]);   // broadcast read
    }
    __syncthreads();

    // restage: W2 + xi rows
    for (int k = t; k < DOUT * DIN; k += 256) wL[k >> 7][k & 127] = pow_[k];
    for (int k = t; k < 16 * DIN; k += 256) {
        const int i = k >> 7, d = k & 127;
        vL[i][d] = x[(size_t)(rbase + i) * DIN + d];
    }
    __syncthreads();

    // phase 2: res[rr] = W2[o,:] . xi[row], combine, write
    float res[4] = {0.f, 0.f, 0.f, 0.f};
    #pragma unroll 4
    for (int d = 0; d < DIN; ++d) {
        float w = wL[o][d];
        #pragma unroll
        for (int rr = 0; rr < 4; ++rr)
            res[rr] = fmaf(w, vL[rq + rr * 4][d], res[rr]);
    }
    const float bias = pwb[o] + pob[o];
    #pragma unroll
    for (int rr = 0; rr < 4; ++rr) {
        const int i = rq + rr * 4;
        out[(size_t)(rbase + i) * DOUT + o] = accp[rr] * invL[i] + res[rr] + bias;
    }
}

// Per-channel batch stats over (B*N, 64); deterministic tree reduction.
__global__ void bn_stats(const float* __restrict__ h, float* __restrict__ stats) {
    const int c = blockIdx.x;
    const int t = threadIdx.x;
    float s = 0.f, s2 = 0.f;
    for (int r = t; r < NTOT; r += 256) {
        float v = h[(size_t)r * DOUT + c];
        s += v; s2 += v * v;
    }
    __shared__ float rs[256], rs2[256];
    rs[t] = s; rs2[t] = s2;
    __syncthreads();
    for (int k = 128; k > 0; k >>= 1) {
        if (t < k) { rs[t] += rs[t + k]; rs2[t] += rs2[t + k]; }
        __syncthreads();
    }
    if (t == 0) {
        const float inv_n = 1.0f / (float)NTOT;
        float mean = rs[0] * inv_n;
        float var = rs2[0] * inv_n - mean * mean;   // biased, as torch BN
        stats[c] = mean;
        stats[DOUT + c] = rsqrtf(var + 1e-5f);
    }
}

__global__ void bn_selu(float* __restrict__ out, const float* __restrict__ stats,
                        const float* __restrict__ gamma, const float* __restrict__ beta) {
    const int idx = blockIdx.x * 256 + threadIdx.x;
    const int c = idx & 63;
    float v = out[idx];
    float y = (v - stats[c]) * stats[DOUT + c] * gamma[c] + beta[c];
    const float scale = 1.0507009873554805f;
    const float alpha = 1.6732632423543772f;
    out[idx] = y > 0.0f ? scale * y : scale * alpha * (__expf(y) - 1.0f);
}

extern "C" void kernel_launch(void* const* d_in, const int* in_sizes, int n_in,
                              void* d_out, int out_size, void* d_ws, size_t ws_size,
                              hipStream_t stream) {
    const float* x    = (const float*)d_in[0];
    const float* apw  = (const float*)d_in[1];
    const float* apb  = (const float*)d_in[2];
    const float* attw = (const float*)d_in[3];
    const float* pww  = (const float*)d_in[4];
    const float* pwb  = (const float*)d_in[5];
    const float* pow_ = (const float*)d_in[6];
    const float* pob  = (const float*)d_in[7];
    const float* gmm  = (const float*)d_in[8];
    const float* bta  = (const float*)d_in[9];
    float* out = (float*)d_out;

    char* ws = (char*)d_ws;
    float* stats = (float*)ws;                               // 512 B (pad 1 KB)
    unsigned short* xbf = (unsigned short*)(ws + 1024);      // 512 KB
    float* pnum = (float*)(ws + 528384);                     // 2 MB  [2][2048][128]
    float* pden = (float*)(ws + 528384 + 2097152);           // 16 KB [2][2048]

    x_to_bf16<<<256, 256, 0, stream>>>(x, xbf);
    gat_main<<<2 * NTOT / TI, 256, 0, stream>>>(x, xbf, apw, apb, attw, pnum, pden);
    combine_proj<<<NTOT / 16, 256, 0, stream>>>(x, pnum, pden, pww, pwb, pow_, pob, out);
    bn_stats<<<DOUT, 256, 0, stream>>>(out, stats);
    bn_selu<<<(NTOT * DOUT) / 256, 256, 0, stream>>>(out, stats, gmm, bta);
}